// Round 9
// baseline (165.837 us; speedup 1.0000x reference)
//
#include <hip/hip_runtime.h>
#include <math.h>

// Problem dims (fixed by the reference)
constexpr int NB  = 16;    // batch
constexpr int NP  = 1024;  // prev points
constexpr int NS  = 4096;  // skip points
constexpr int CP  = 256;   // prev channels
constexpr int CS  = 128;   // skip channels
constexpr int CIN = 384;   // CP + CS
constexpr int CO  = 256;   // output channels

constexpr int NCHUNK = 16;          // prev-point chunks for topk parallelism
constexpr int CHPTS  = NP / NCHUNK; // 64

typedef unsigned int uint;
typedef unsigned short ushort_t;
typedef __attribute__((ext_vector_type(8))) short short8;
typedef __attribute__((ext_vector_type(8))) unsigned short us8;
typedef __attribute__((ext_vector_type(4))) float f32x4;

__device__ __forceinline__ ushort_t f2bf(float f) {
  uint u = __float_as_uint(f);
  uint r = (u + 0x7fffu + ((u >> 16) & 1u)) >> 16;   // RNE
  return (ushort_t)r;
}
__device__ __forceinline__ float bf2f(ushort_t u) {
  return __uint_as_float(((uint)u) << 16);
}

__device__ __forceinline__ void gload16(const void* g, void* l) {
  __builtin_amdgcn_global_load_lds(
      (const __attribute__((address_space(1))) uint*)g,
      (__attribute__((address_space(3))) uint*)l, 16, 0, 0);
}

// Packed-key top-3 step (set-level correctness; masked-dist err <= 2^-13 rel).
__device__ __forceinline__ void tkp(float pxv, float pyv, float pzv, int pi,
                                    float qx, float qy, float qz,
                                    float& k0, float& k1, float& k2,
                                    float& rsum) {
  float dx = pxv - qx, dy = pyv - qy, dz = pzv - qz;
  float sq = fmaf(dz, dz, fmaf(dy, dy, fmaf(dx, dx, 1e-16f)));
  rsum += __builtin_amdgcn_rsqf(sq);
  float k = __uint_as_float((__float_as_uint(sq) & 0xFFFFFC00u) | (uint)pi);
  k2 = __builtin_amdgcn_fmed3f(k1, k2, k);
  k1 = __builtin_amdgcn_fmed3f(k0, k1, k);
  k0 = fminf(k0, k);
}

// ---------------------------------------------------------------------------
// topk stage 1 (unchanged)
__global__ __launch_bounds__(256) void topk_chunk_kernel(
    const float* __restrict__ xyz_prev, const float* __restrict__ xyz_skip,
    float* __restrict__ pbuf) {
  __shared__ float px[CHPTS], py[CHPTS], pz[CHPTS];
  int q  = blockIdx.y;
  int b  = blockIdx.z;
  int tid = threadIdx.x;
  if (tid < CHPTS) {
    const float* xp = xyz_prev + ((size_t)b * NP + q * CHPTS + tid) * 3;
    px[tid] = xp[0]; py[tid] = xp[1]; pz[tid] = xp[2];
  }
  __syncthreads();
  int nA = blockIdx.x * 512 + tid;
  int nB = nA + 256;
  const float* xqA = xyz_skip + ((size_t)b * NS + nA) * 3;
  const float* xqB = xyz_skip + ((size_t)b * NS + nB) * 3;
  float qxA = xqA[0], qyA = xqA[1], qzA = xqA[2];
  float qxB = xqB[0], qyB = xqB[1], qzB = xqB[2];
  float kA0 = INFINITY, kA1 = INFINITY, kA2 = INFINITY;
  float kB0 = INFINITY, kB1 = INFINITY, kB2 = INFINITY;
  float rsA = 0.f, rsB = 0.f;
  int pbase = q * CHPTS;
  for (int p = 0; p < CHPTS; p += 4) {
    float4 X = *(const float4*)&px[p];
    float4 Y = *(const float4*)&py[p];
    float4 Z = *(const float4*)&pz[p];
    tkp(X.x, Y.x, Z.x, pbase + p + 0, qxA, qyA, qzA, kA0, kA1, kA2, rsA);
    tkp(X.x, Y.x, Z.x, pbase + p + 0, qxB, qyB, qzB, kB0, kB1, kB2, rsB);
    tkp(X.y, Y.y, Z.y, pbase + p + 1, qxA, qyA, qzA, kA0, kA1, kA2, rsA);
    tkp(X.y, Y.y, Z.y, pbase + p + 1, qxB, qyB, qzB, kB0, kB1, kB2, rsB);
    tkp(X.z, Y.z, Z.z, pbase + p + 2, qxA, qyA, qzA, kA0, kA1, kA2, rsA);
    tkp(X.z, Y.z, Z.z, pbase + p + 2, qxB, qyB, qzB, kB0, kB1, kB2, rsB);
    tkp(X.w, Y.w, Z.w, pbase + p + 3, qxA, qyA, qzA, kA0, kA1, kA2, rsA);
    tkp(X.w, Y.w, Z.w, pbase + p + 3, qxB, qyB, qzB, kB0, kB1, kB2, rsB);
  }
  size_t PA = ((size_t)(b * NCHUNK + q) * NS + nA) * 4;
  size_t PB = ((size_t)(b * NCHUNK + q) * NS + nB) * 4;
  *(float4*)(pbuf + PA) = make_float4(kA0, kA1, kA2, rsA);
  *(float4*)(pbuf + PB) = make_float4(kB0, kB1, kB2, rsB);
}

// topk stage 2 (unchanged)
__global__ __launch_bounds__(256) void topk_merge_kernel(
    const float* __restrict__ pbuf, float* __restrict__ w3,
    int* __restrict__ idx3) {
  int gid = blockIdx.x * 256 + threadIdx.x;  // = b*NS + n
  int b = gid >> 12;
  int n = gid & (NS - 1);
  float k0 = INFINITY, k1 = INFINITY, k2 = INFINITY;
  float rsum = 0.f;
  #pragma unroll 4
  for (int q = 0; q < NCHUNK; q++) {
    float4 v = *(const float4*)(pbuf + ((size_t)(b * NCHUNK + q) * NS + n) * 4);
    rsum += v.w;
    k2 = __builtin_amdgcn_fmed3f(k1, k2, v.x);
    k1 = __builtin_amdgcn_fmed3f(k0, k1, v.x);
    k0 = fminf(k0, v.x);
    k2 = __builtin_amdgcn_fmed3f(k1, k2, v.y);
    k1 = __builtin_amdgcn_fmed3f(k0, k1, v.y);
    k0 = fminf(k0, v.y);
    k2 = __builtin_amdgcn_fmed3f(k1, k2, v.z);
    k1 = __builtin_amdgcn_fmed3f(k0, k1, v.z);
    k0 = fminf(k0, v.z);
  }
  float inv = 1.0f / rsum;
  uint u0 = __float_as_uint(k0), u1 = __float_as_uint(k1), u2 = __float_as_uint(k2);
  float d0 = __uint_as_float(u0 & 0xFFFFFC00u);
  float d1 = __uint_as_float(u1 & 0xFFFFFC00u);
  float d2 = __uint_as_float(u2 & 0xFFFFFC00u);
  size_t base = (size_t)gid * 3;
  w3[base + 0] = __builtin_amdgcn_rsqf(d0) * inv;
  w3[base + 1] = __builtin_amdgcn_rsqf(d1) * inv;
  w3[base + 2] = __builtin_amdgcn_rsqf(d2) * inv;
  idx3[base + 0] = (int)(u0 & 1023u);
  idx3[base + 1] = (int)(u1 & 1023u);
  idx3[base + 2] = (int)(u2 & 1023u);
}

// ---------------------------------------------------------------------------
// W fp32 -> bf16; block 0 also zeros the BN stats.
__global__ __launch_bounds__(256) void wcast_kernel(
    const float* __restrict__ W1, const float* __restrict__ W2,
    ushort_t* __restrict__ W1b, ushort_t* __restrict__ W2b,
    float* __restrict__ st1, float* __restrict__ st2) {
  int tid = threadIdx.x;
  if (blockIdx.x == 0) {
    st1[tid] = 0.f; st1[tid + 256] = 0.f;
    st2[tid] = 0.f; st2[tid + 256] = 0.f;
  }
  int t = blockIdx.x * 256 + tid;
  int n1 = CO * CIN / 4;
  if (t < n1) {
    float4 v = *(const float4*)(W1 + t * 4);
    ushort4 o; o.x = f2bf(v.x); o.y = f2bf(v.y); o.z = f2bf(v.z); o.w = f2bf(v.w);
    *(ushort4*)(W1b + t * 4) = o;
  } else {
    int u = t - n1;
    float4 v = *(const float4*)(W2 + u * 4);
    ushort4 o; o.x = f2bf(v.x); o.y = f2bf(v.y); o.z = f2bf(v.z); o.w = f2bf(v.w);
    *(ushort4*)(W2b + u * 4) = o;
  }
}

// ---------------------------------------------------------------------------
// Transpose points_prev [b][256][1024] f32 -> pptT [b][1024][256] bf16.
__global__ __launch_bounds__(256) void ppT_kernel(
    const float* __restrict__ pp, ushort_t* __restrict__ pptT) {
  __shared__ float tl[64][65];
  int p0 = blockIdx.x * 64, c0 = blockIdx.y * 64, b = blockIdx.z;
  int tid = threadIdx.x;
  const float* P = pp + (size_t)b * CP * NP;
  int pi4 = (tid & 15) * 4, ci = tid >> 4;
  #pragma unroll
  for (int r = 0; r < 4; r++) {
    int cc = ci + 16 * r;
    float4 v = *(const float4*)(P + (size_t)(c0 + cc) * NP + p0 + pi4);
    tl[cc][pi4] = v.x; tl[cc][pi4 + 1] = v.y; tl[cc][pi4 + 2] = v.z; tl[cc][pi4 + 3] = v.w;
  }
  __syncthreads();
  ushort_t* O = pptT + (size_t)b * NP * CP;
  int ci4 = (tid & 15) * 4, pi = tid >> 4;
  #pragma unroll
  for (int r = 0; r < 4; r++) {
    int pr = pi + 16 * r;
    ushort4 o;
    o.x = f2bf(tl[ci4 + 0][pr]); o.y = f2bf(tl[ci4 + 1][pr]);
    o.z = f2bf(tl[ci4 + 2][pr]); o.w = f2bf(tl[ci4 + 3][pr]);
    *(ushort4*)(O + (size_t)(p0 + pr) * CP + c0 + ci4) = o;
  }
}

// Transpose points_skip [b][128][4096] f32 -> x1[b][n][256..383] bf16.
__global__ __launch_bounds__(256) void skipT_kernel(
    const float* __restrict__ sk, ushort_t* __restrict__ x1) {
  __shared__ float tl[64][65];
  int n0 = blockIdx.x * 64, c0 = blockIdx.y * 64, b = blockIdx.z;
  int tid = threadIdx.x;
  const float* S = sk + (size_t)b * CS * NS;
  int ni4 = (tid & 15) * 4, ci = tid >> 4;
  #pragma unroll
  for (int r = 0; r < 4; r++) {
    int cc = ci + 16 * r;
    float4 v = *(const float4*)(S + (size_t)(c0 + cc) * NS + n0 + ni4);
    tl[cc][ni4] = v.x; tl[cc][ni4 + 1] = v.y; tl[cc][ni4 + 2] = v.z; tl[cc][ni4 + 3] = v.w;
  }
  __syncthreads();
  ushort_t* O = x1 + (size_t)b * NS * CIN;
  int ci4 = (tid & 15) * 4, ni = tid >> 4;
  #pragma unroll
  for (int r = 0; r < 4; r++) {
    int nr = ni + 16 * r;
    ushort4 o;
    o.x = f2bf(tl[ci4 + 0][nr]); o.y = f2bf(tl[ci4 + 1][nr]);
    o.z = f2bf(tl[ci4 + 2][nr]); o.w = f2bf(tl[ci4 + 3][nr]);
    *(ushort4*)(O + (size_t)(n0 + nr) * CIN + CP + c0 + ci4) = o;
  }
}

// Interp: x1[b][n][0..255] = sum_k w3[k] * pptT[idx[k]][c].
__global__ __launch_bounds__(256) void interp_kernel(
    const ushort_t* __restrict__ pptT, const float* __restrict__ w3,
    const int* __restrict__ idx3, ushort_t* __restrict__ x1) {
  int tid = threadIdx.x;
  int nl = tid >> 6, l = tid & 63;
  int b = blockIdx.y;
  int n = blockIdx.x * 4 + nl;
  size_t nb = (size_t)b * NS + n;
  int j0 = idx3[nb * 3 + 0], j1 = idx3[nb * 3 + 1], j2 = idx3[nb * 3 + 2];
  float w0 = w3[nb * 3 + 0], w1 = w3[nb * 3 + 1], w2 = w3[nb * 3 + 2];
  const ushort_t* P = pptT + (size_t)b * NP * CP;
  int c = l * 4;
  ushort4 g0 = *(const ushort4*)(P + (size_t)j0 * CP + c);
  ushort4 g1 = *(const ushort4*)(P + (size_t)j1 * CP + c);
  ushort4 g2 = *(const ushort4*)(P + (size_t)j2 * CP + c);
  ushort4 o;
  o.x = f2bf(w0 * bf2f(g0.x) + w1 * bf2f(g1.x) + w2 * bf2f(g2.x));
  o.y = f2bf(w0 * bf2f(g0.y) + w1 * bf2f(g1.y) + w2 * bf2f(g2.y));
  o.z = f2bf(w0 * bf2f(g0.z) + w1 * bf2f(g1.z) + w2 * bf2f(g2.z));
  o.w = f2bf(w0 * bf2f(g0.w) + w1 * bf2f(g1.w) + w2 * bf2f(g2.w));
  *(ushort4*)(x1 + nb * CIN + c) = o;
}

// ---------------------------------------------------------------------------
// MFMA GEMM, BK=64, single-buffered 2-barrier loop (round-6 semantics, half
// the barrier drains). LDS rows are 128B => XOR swizzle chunk^=(row&7), applied
// BOTH sides: pre-swizzled gload source + swizzled ds_read (rule #21).
// MODE 0: gemm1, X = x1 [b][n][384], pure global_load_lds staging.
// MODE 1: gemm2, X = relu(a1*y1+s1) from y1b [b][n][256], reg-staged act.
// 128x128 tile, 4 waves, 4x4 frags of 16x16x32; bf16 out via LDS-coalesced
// epilogue; BN stats accumulated; MODE1 computes BN1 affine in prologue.
template <int MODE>
__global__ __launch_bounds__(256, 4) void gemm_bk64_kernel(
    const ushort_t* __restrict__ X, const ushort_t* __restrict__ Wb,
    ushort_t* __restrict__ Yb, float* __restrict__ stats,
    const float* __restrict__ stats_in, const float* __restrict__ g_in,
    const float* __restrict__ bt_in) {
  constexpr int KD = MODE ? CO : CIN;
  constexpr int NT = KD / 64;            // 4 or 6
  __shared__ __align__(16) char lds_raw[33792];  // X 16K | W 16K; epi 128x132
  ushort_t* ldsX = (ushort_t*)lds_raw;
  ushort_t* ldsW = (ushort_t*)(lds_raw + 16384);
  __shared__ float ssum[128], ssq[128];
  __shared__ float a1s[MODE ? CO : 1], s1s[MODE ? CO : 1];

  int tid = threadIdx.x;
  int w = tid >> 6, l = tid & 63;
  int bid = blockIdx.x;
  int by = (bid >> 3) & 1;
  int s = (bid & 7) + 8 * (bid >> 4);
  int bx = s & 31, bz = s >> 5;
  int n0 = bx * 128;
  if (tid < 128) { ssum[tid] = 0.f; ssq[tid] = 0.f; }
  if constexpr (MODE == 1) {
    float cnt = (float)NB * (float)NS;
    float m = stats_in[tid] / cnt;
    float var = stats_in[CO + tid] / cnt - m * m;
    var = fmaxf(var, 0.f);
    float invs = rsqrtf(var + 1e-5f);
    float av = g_in[tid] * invs;
    a1s[tid] = av; s1s[tid] = bt_in[tid] - m * av;
  }
  __syncthreads();

  // gload geometry (per wave, 4 groups of 8 rows; lane l covers chunk l of
  // the 1KB group): row = grpbase + (l>>3), phys chunk = l&7, logical chunk
  // = (l&7) ^ (row&7) with row&7 == (l>>3).
  int grow = l >> 3;                 // 0..7
  int glc  = (l & 7) ^ grow;         // logical 16B chunk within 128B row
  // MODE1 reg-stage geometry: thread handles chunks tid+256c (c=0..3):
  // row = (tid>>3)+32c, phys = tid&7, logical lc constant per thread.
  int trow = tid >> 3;               // base row (0..31)
  int tlc  = (tid & 7) ^ (trow & 7); // logical chunk
  const ushort_t* Xb = X + (size_t)bz * NS * KD;

  f32x4 acc[4][4];
  #pragma unroll
  for (int i = 0; i < 4; i++)
    #pragma unroll
    for (int j = 0; j < 4; j++) acc[i][j] = {0.f, 0.f, 0.f, 0.f};

  int wn = (w & 1) * 64, wo = (w >> 1) * 64;
  int lr = l & 15, lk = l >> 4;

  for (int t = 0; t < NT; t++) {
    int k0 = t * 64;
    // ---- stage W (both modes): 4 gload16 per wave
    #pragma unroll
    for (int i = 0; i < 4; i++) {
      int row = w * 32 + i * 8 + grow;
      gload16(Wb + (size_t)(by * 128 + row) * KD + k0 + glc * 8,
              &ldsW[(w * 32 + i * 8) * 64]);
    }
    // ---- stage X
    if constexpr (MODE == 0) {
      #pragma unroll
      for (int i = 0; i < 4; i++) {
        int row = w * 32 + i * 8 + grow;
        gload16(Xb + (size_t)(n0 + row) * KD + k0 + glc * 8,
                &ldsX[(w * 32 + i * 8) * 64]);
      }
    } else {
      #pragma unroll
      for (int c = 0; c < 4; c++) {
        int row = trow + 32 * c;
        us8 v = *(const us8*)(Xb + (size_t)(n0 + row) * KD + k0 + tlc * 8);
        const float* ap = &a1s[k0 + tlc * 8];
        const float* sp = &s1s[k0 + tlc * 8];
        us8 o;
        #pragma unroll
        for (int e = 0; e < 8; e++)
          o[e] = f2bf(fmaxf(fmaf(ap[e], bf2f(v[e]), sp[e]), 0.f));
        *(us8*)&ldsX[(tid + 256 * c) * 8] = o;
      }
    }
    __syncthreads();   // waits vmcnt(0)+lgkmcnt(0): tiles landed
    // ---- compute: 2 k-subtiles x 16 MFMA
    #pragma unroll
    for (int ks = 0; ks < 2; ks++) {
      short8 af[4], bfr[4];
      #pragma unroll
      for (int i = 0; i < 4; i++) {
        int rr = wn + i * 16 + lr;
        int pc = (ks * 4 + lk) ^ (rr & 7);
        af[i] = *(const short8*)&ldsX[rr * 64 + pc * 8];
      }
      #pragma unroll
      for (int j = 0; j < 4; j++) {
        int rr = wo + j * 16 + lr;
        int pc = (ks * 4 + lk) ^ (rr & 7);
        bfr[j] = *(const short8*)&ldsW[rr * 64 + pc * 8];
      }
      __builtin_amdgcn_s_setprio(1);
      #pragma unroll
      for (int i = 0; i < 4; i++)
        #pragma unroll
        for (int j = 0; j < 4; j++)
          acc[i][j] = __builtin_amdgcn_mfma_f32_16x16x32_bf16(af[i], bfr[j], acc[i][j], 0, 0, 0);
      __builtin_amdgcn_s_setprio(0);
    }
    __syncthreads();   // compute done before next stage overwrites
  }

  // ---- epilogue: BN stats from regs; tile -> LDS; coalesced row stores
  #pragma unroll
  for (int j = 0; j < 4; j++) {
    int ol = wo + j * 16 + lr;
    float ps = 0.f, pq = 0.f;
    #pragma unroll
    for (int i = 0; i < 4; i++)
      #pragma unroll
      for (int rg = 0; rg < 4; rg++) { float v = acc[i][j][rg]; ps += v; pq += v * v; }
    atomicAdd(&ssum[ol], ps);
    atomicAdd(&ssq[ol], pq);
  }
  ushort_t* lout = (ushort_t*)lds_raw;   // [128][132]
  #pragma unroll
  for (int i = 0; i < 4; i++)
    #pragma unroll
    for (int j = 0; j < 4; j++)
      #pragma unroll
      for (int rg = 0; rg < 4; rg++) {
        int nl = wn + i * 16 + lk * 4 + rg;
        int ol = wo + j * 16 + lr;
        lout[nl * 132 + ol] = f2bf(acc[i][j][rg]);
      }
  __syncthreads();
  {
    int row = tid >> 1, half = tid & 1;
    const ushort_t* src = lout + row * 132 + half * 64;
    ushort_t* dst = Yb + ((size_t)bz * NS + n0 + row) * CO + by * 128 + half * 64;
    #pragma unroll
    for (int k = 0; k < 8; k++)
      *(us8*)(dst + k * 8) = *(const us8*)(src + k * 8);
  }
  if (tid < 128) {
    atomicAdd(&stats[by * 128 + tid], ssum[tid]);
    atomicAdd(&stats[CO + by * 128 + tid], ssq[tid]);
  }
}

// Final BN2+ReLU with transpose, bf16 in [b][n][o] -> f32 out [b][o][n].
__global__ __launch_bounds__(256) void bnrelu_tr_kernel(
    const ushort_t* __restrict__ y2b, const float* __restrict__ stats_in,
    const float* __restrict__ g_in, const float* __restrict__ bt_in,
    float* __restrict__ out) {
  __shared__ float tl[64][65];
  __shared__ float a2s[64], s2s[64];
  int n0 = blockIdx.x * 64, o0 = blockIdx.y * 64, b = blockIdx.z;
  const ushort_t* Y = y2b + (size_t)b * NS * CO;
  int tid = threadIdx.x;
  if (tid < 64) {
    int o = o0 + tid;
    float cnt = (float)NB * (float)NS;
    float m = stats_in[o] / cnt;
    float var = stats_in[CO + o] / cnt - m * m;
    var = fmaxf(var, 0.f);
    float invs = rsqrtf(var + 1e-5f);
    float av = g_in[o] * invs;
    a2s[tid] = av; s2s[tid] = bt_in[o] - m * av;
  }
  int o8 = (tid & 7) * 8, row = tid >> 3;
  #pragma unroll
  for (int r = 0; r < 2; r++) {
    int ii = row + 32 * r;
    const ushort_t* src = Y + (size_t)(n0 + ii) * CO + o0 + o8;
    ushort4 v0 = *(const ushort4*)(src);
    ushort4 v1 = *(const ushort4*)(src + 4);
    tl[ii][o8 + 0] = bf2f(v0.x); tl[ii][o8 + 1] = bf2f(v0.y);
    tl[ii][o8 + 2] = bf2f(v0.z); tl[ii][o8 + 3] = bf2f(v0.w);
    tl[ii][o8 + 4] = bf2f(v1.x); tl[ii][o8 + 5] = bf2f(v1.y);
    tl[ii][o8 + 6] = bf2f(v1.z); tl[ii][o8 + 7] = bf2f(v1.w);
  }
  __syncthreads();
  float* O = out + (size_t)b * CO * NS;
  int ii4 = (tid & 15) * 4, j = tid >> 4;
  #pragma unroll
  for (int r = 0; r < 4; r++) {
    int jj = j + 16 * r;
    float av = a2s[jj], sv = s2s[jj];
    float4 v;
    v.x = fmaxf(fmaf(av, tl[ii4 + 0][jj], sv), 0.f);
    v.y = fmaxf(fmaf(av, tl[ii4 + 1][jj], sv), 0.f);
    v.z = fmaxf(fmaf(av, tl[ii4 + 2][jj], sv), 0.f);
    v.w = fmaxf(fmaf(av, tl[ii4 + 3][jj], sv), 0.f);
    *(float4*)(O + (size_t)(o0 + jj) * NS + n0 + ii4) = v;
  }
}

extern "C" void kernel_launch(void* const* d_in, const int* in_sizes, int n_in,
                              void* d_out, int out_size, void* d_ws, size_t ws_size,
                              hipStream_t stream) {
  const float* xyz_prev    = (const float*)d_in[0];
  const float* xyz_skip    = (const float*)d_in[1];
  const float* points_prev = (const float*)d_in[2];
  const float* points_skip = (const float*)d_in[3];
  const float* W1 = (const float*)d_in[4];
  const float* g1 = (const float*)d_in[5];
  const float* b1 = (const float*)d_in[6];
  const float* W2 = (const float*)d_in[7];
  const float* g2 = (const float*)d_in[8];
  const float* b2 = (const float*)d_in[9];
  float* out = (float*)d_out;

  // workspace layout (256B-aligned sequential allocs)
  char* W = (char*)d_ws;
  size_t off = 0;
  auto alloc = [&](size_t bytes) {
    size_t o = off; off = (off + bytes + 255) & ~(size_t)255; return o;
  };
  ushort_t* x1   = (ushort_t*)(W + alloc((size_t)NB * NS * CIN * 2));  // 50.3MB
  ushort_t* y1b  = (ushort_t*)(W + alloc((size_t)NB * NS * CO * 2));   // 33.6MB
  ushort_t* pptT = (ushort_t*)(W + alloc((size_t)NB * NP * CP * 2));   // 8.4MB
  ushort_t* W1b  = (ushort_t*)(W + alloc((size_t)CO * CIN * 2));
  ushort_t* W2b  = (ushort_t*)(W + alloc((size_t)CO * CO * 2));
  float* w3   = (float*)(W + alloc((size_t)NB * NS * 3 * 4));
  int*   idx3 = (int*)(W + alloc((size_t)NB * NS * 3 * 4));
  float* st1  = (float*)(W + alloc(512 * 4));
  float* st2  = (float*)(W + alloc(512 * 4));
  size_t y2_off = alloc((size_t)NB * NS * CO * 2);                     // 33.6MB bf16
  bool full = (ws_size >= off);
  ushort_t* y2b = full ? (ushort_t*)(W + y2_off) : (ushort_t*)d_out;
  // pbuf (16.8MB, transient, consumed before any y2 write) aliases y2 region
  float* pbuf = full ? (float*)(W + y2_off) : (float*)d_out;

  hipLaunchKernelGGL(topk_chunk_kernel, dim3(NS / 512, NCHUNK, NB), dim3(256), 0,
                     stream, xyz_prev, xyz_skip, pbuf);
  hipLaunchKernelGGL(topk_merge_kernel, dim3(NB * NS / 256), dim3(256), 0, stream,
                     pbuf, w3, idx3);
  hipLaunchKernelGGL(wcast_kernel, dim3((CO * CIN / 4 + CO * CO / 4 + 255) / 256),
                     dim3(256), 0, stream, W1, W2, W1b, W2b, st1, st2);
  hipLaunchKernelGGL(ppT_kernel, dim3(NP / 64, CP / 64, NB), dim3(256), 0, stream,
                     points_prev, pptT);
  hipLaunchKernelGGL(skipT_kernel, dim3(NS / 64, CS / 64, NB), dim3(256), 0, stream,
                     points_skip, x1);
  hipLaunchKernelGGL(interp_kernel, dim3(NS / 4, NB), dim3(256), 0, stream,
                     pptT, w3, idx3, x1);
  hipLaunchKernelGGL((gemm_bk64_kernel<0>), dim3(1024), dim3(256), 0, stream,
                     x1, W1b, y1b, st1, (const float*)nullptr,
                     (const float*)nullptr, (const float*)nullptr);
  hipLaunchKernelGGL((gemm_bk64_kernel<1>), dim3(1024), dim3(256), 0, stream,
                     y1b, W2b, y2b, st2, st1, g1, b1);
  if (full) {
    hipLaunchKernelGGL(bnrelu_tr_kernel, dim3(NS / 64, CO / 64, NB), dim3(256), 0,
                       stream, y2b, st2, g2, b2, out);
  } else {
    float* stage = (float*)d_ws;
    hipLaunchKernelGGL(bnrelu_tr_kernel, dim3(NS / 64, CO / 64, NB), dim3(256), 0,
                       stream, y2b, st2, g2, b2, stage);
    hipMemcpyAsync(out, stage, (size_t)NB * NS * CO * 4, hipMemcpyDeviceToDevice,
                   stream);
  }
}

// Round 10
// 163.232 us; speedup vs baseline: 1.0160x; 1.0160x over previous
//
#include <hip/hip_runtime.h>
#include <math.h>

// Problem dims (fixed by the reference)
constexpr int NB  = 16;    // batch
constexpr int NP  = 1024;  // prev points
constexpr int NS  = 4096;  // skip points
constexpr int CP  = 256;   // prev channels
constexpr int CS  = 128;   // skip channels
constexpr int CIN = 384;   // CP + CS
constexpr int CO  = 256;   // output channels

constexpr int NCHUNK = 16;          // prev-point chunks for topk parallelism
constexpr int CHPTS  = NP / NCHUNK; // 64

typedef unsigned int uint;
typedef unsigned short ushort_t;
typedef __attribute__((ext_vector_type(8))) short short8;
typedef __attribute__((ext_vector_type(8))) unsigned short us8;
typedef __attribute__((ext_vector_type(4))) float f32x4;

__device__ __forceinline__ ushort_t f2bf(float f) {
  uint u = __float_as_uint(f);
  uint r = (u + 0x7fffu + ((u >> 16) & 1u)) >> 16;   // RNE
  return (ushort_t)r;
}
__device__ __forceinline__ float bf2f(ushort_t u) {
  return __uint_as_float(((uint)u) << 16);
}

__device__ __forceinline__ void gload16(const void* g, void* l) {
  __builtin_amdgcn_global_load_lds(
      (const __attribute__((address_space(1))) uint*)g,
      (__attribute__((address_space(3))) uint*)l, 16, 0, 0);
}

// Packed-key top-3 step (set-level correctness; masked-dist err <= 2^-13 rel).
__device__ __forceinline__ void tkp(float pxv, float pyv, float pzv, int pi,
                                    float qx, float qy, float qz,
                                    float& k0, float& k1, float& k2,
                                    float& rsum) {
  float dx = pxv - qx, dy = pyv - qy, dz = pzv - qz;
  float sq = fmaf(dz, dz, fmaf(dy, dy, fmaf(dx, dx, 1e-16f)));
  rsum += __builtin_amdgcn_rsqf(sq);
  float k = __uint_as_float((__float_as_uint(sq) & 0xFFFFFC00u) | (uint)pi);
  k2 = __builtin_amdgcn_fmed3f(k1, k2, k);
  k1 = __builtin_amdgcn_fmed3f(k0, k1, k);
  k0 = fminf(k0, k);
}

// ---------------------------------------------------------------------------
// topk stage 1 (unchanged)
__global__ __launch_bounds__(256) void topk_chunk_kernel(
    const float* __restrict__ xyz_prev, const float* __restrict__ xyz_skip,
    float* __restrict__ pbuf) {
  __shared__ float px[CHPTS], py[CHPTS], pz[CHPTS];
  int q  = blockIdx.y;
  int b  = blockIdx.z;
  int tid = threadIdx.x;
  if (tid < CHPTS) {
    const float* xp = xyz_prev + ((size_t)b * NP + q * CHPTS + tid) * 3;
    px[tid] = xp[0]; py[tid] = xp[1]; pz[tid] = xp[2];
  }
  __syncthreads();
  int nA = blockIdx.x * 512 + tid;
  int nB = nA + 256;
  const float* xqA = xyz_skip + ((size_t)b * NS + nA) * 3;
  const float* xqB = xyz_skip + ((size_t)b * NS + nB) * 3;
  float qxA = xqA[0], qyA = xqA[1], qzA = xqA[2];
  float qxB = xqB[0], qyB = xqB[1], qzB = xqB[2];
  float kA0 = INFINITY, kA1 = INFINITY, kA2 = INFINITY;
  float kB0 = INFINITY, kB1 = INFINITY, kB2 = INFINITY;
  float rsA = 0.f, rsB = 0.f;
  int pbase = q * CHPTS;
  for (int p = 0; p < CHPTS; p += 4) {
    float4 X = *(const float4*)&px[p];
    float4 Y = *(const float4*)&py[p];
    float4 Z = *(const float4*)&pz[p];
    tkp(X.x, Y.x, Z.x, pbase + p + 0, qxA, qyA, qzA, kA0, kA1, kA2, rsA);
    tkp(X.x, Y.x, Z.x, pbase + p + 0, qxB, qyB, qzB, kB0, kB1, kB2, rsB);
    tkp(X.y, Y.y, Z.y, pbase + p + 1, qxA, qyA, qzA, kA0, kA1, kA2, rsA);
    tkp(X.y, Y.y, Z.y, pbase + p + 1, qxB, qyB, qzB, kB0, kB1, kB2, rsB);
    tkp(X.z, Y.z, Z.z, pbase + p + 2, qxA, qyA, qzA, kA0, kA1, kA2, rsA);
    tkp(X.z, Y.z, Z.z, pbase + p + 2, qxB, qyB, qzB, kB0, kB1, kB2, rsB);
    tkp(X.w, Y.w, Z.w, pbase + p + 3, qxA, qyA, qzA, kA0, kA1, kA2, rsA);
    tkp(X.w, Y.w, Z.w, pbase + p + 3, qxB, qyB, qzB, kB0, kB1, kB2, rsB);
  }
  size_t PA = ((size_t)(b * NCHUNK + q) * NS + nA) * 4;
  size_t PB = ((size_t)(b * NCHUNK + q) * NS + nB) * 4;
  *(float4*)(pbuf + PA) = make_float4(kA0, kA1, kA2, rsA);
  *(float4*)(pbuf + PB) = make_float4(kB0, kB1, kB2, rsB);
}

// topk stage 2 (unchanged)
__global__ __launch_bounds__(256) void topk_merge_kernel(
    const float* __restrict__ pbuf, float* __restrict__ w3,
    int* __restrict__ idx3) {
  int gid = blockIdx.x * 256 + threadIdx.x;  // = b*NS + n
  int b = gid >> 12;
  int n = gid & (NS - 1);
  float k0 = INFINITY, k1 = INFINITY, k2 = INFINITY;
  float rsum = 0.f;
  #pragma unroll 4
  for (int q = 0; q < NCHUNK; q++) {
    float4 v = *(const float4*)(pbuf + ((size_t)(b * NCHUNK + q) * NS + n) * 4);
    rsum += v.w;
    k2 = __builtin_amdgcn_fmed3f(k1, k2, v.x);
    k1 = __builtin_amdgcn_fmed3f(k0, k1, v.x);
    k0 = fminf(k0, v.x);
    k2 = __builtin_amdgcn_fmed3f(k1, k2, v.y);
    k1 = __builtin_amdgcn_fmed3f(k0, k1, v.y);
    k0 = fminf(k0, v.y);
    k2 = __builtin_amdgcn_fmed3f(k1, k2, v.z);
    k1 = __builtin_amdgcn_fmed3f(k0, k1, v.z);
    k0 = fminf(k0, v.z);
  }
  float inv = 1.0f / rsum;
  uint u0 = __float_as_uint(k0), u1 = __float_as_uint(k1), u2 = __float_as_uint(k2);
  float d0 = __uint_as_float(u0 & 0xFFFFFC00u);
  float d1 = __uint_as_float(u1 & 0xFFFFFC00u);
  float d2 = __uint_as_float(u2 & 0xFFFFFC00u);
  size_t base = (size_t)gid * 3;
  w3[base + 0] = __builtin_amdgcn_rsqf(d0) * inv;
  w3[base + 1] = __builtin_amdgcn_rsqf(d1) * inv;
  w3[base + 2] = __builtin_amdgcn_rsqf(d2) * inv;
  idx3[base + 0] = (int)(u0 & 1023u);
  idx3[base + 1] = (int)(u1 & 1023u);
  idx3[base + 2] = (int)(u2 & 1023u);
}

// ---------------------------------------------------------------------------
// W fp32 -> bf16; block 0 also zeros the BN stats.
__global__ __launch_bounds__(256) void wcast_kernel(
    const float* __restrict__ W1, const float* __restrict__ W2,
    ushort_t* __restrict__ W1b, ushort_t* __restrict__ W2b,
    float* __restrict__ st1, float* __restrict__ st2) {
  int tid = threadIdx.x;
  if (blockIdx.x == 0) {
    st1[tid] = 0.f; st1[tid + 256] = 0.f;
    st2[tid] = 0.f; st2[tid + 256] = 0.f;
  }
  int t = blockIdx.x * 256 + tid;
  int n1 = CO * CIN / 4;
  if (t < n1) {
    float4 v = *(const float4*)(W1 + t * 4);
    ushort4 o; o.x = f2bf(v.x); o.y = f2bf(v.y); o.z = f2bf(v.z); o.w = f2bf(v.w);
    *(ushort4*)(W1b + t * 4) = o;
  } else {
    int u = t - n1;
    float4 v = *(const float4*)(W2 + u * 4);
    ushort4 o; o.x = f2bf(v.x); o.y = f2bf(v.y); o.z = f2bf(v.z); o.w = f2bf(v.w);
    *(ushort4*)(W2b + u * 4) = o;
  }
}

// ---------------------------------------------------------------------------
// Transpose points_prev [b][256][1024] f32 -> pptT [b][1024][256] bf16.
__global__ __launch_bounds__(256) void ppT_kernel(
    const float* __restrict__ pp, ushort_t* __restrict__ pptT) {
  __shared__ float tl[64][65];
  int p0 = blockIdx.x * 64, c0 = blockIdx.y * 64, b = blockIdx.z;
  int tid = threadIdx.x;
  const float* P = pp + (size_t)b * CP * NP;
  int pi4 = (tid & 15) * 4, ci = tid >> 4;
  #pragma unroll
  for (int r = 0; r < 4; r++) {
    int cc = ci + 16 * r;
    float4 v = *(const float4*)(P + (size_t)(c0 + cc) * NP + p0 + pi4);
    tl[cc][pi4] = v.x; tl[cc][pi4 + 1] = v.y; tl[cc][pi4 + 2] = v.z; tl[cc][pi4 + 3] = v.w;
  }
  __syncthreads();
  ushort_t* O = pptT + (size_t)b * NP * CP;
  int ci4 = (tid & 15) * 4, pi = tid >> 4;
  #pragma unroll
  for (int r = 0; r < 4; r++) {
    int pr = pi + 16 * r;
    ushort4 o;
    o.x = f2bf(tl[ci4 + 0][pr]); o.y = f2bf(tl[ci4 + 1][pr]);
    o.z = f2bf(tl[ci4 + 2][pr]); o.w = f2bf(tl[ci4 + 3][pr]);
    *(ushort4*)(O + (size_t)(p0 + pr) * CP + c0 + ci4) = o;
  }
}

// Transpose points_skip [b][128][4096] f32 -> x1[b][n][256..383] bf16.
__global__ __launch_bounds__(256) void skipT_kernel(
    const float* __restrict__ sk, ushort_t* __restrict__ x1) {
  __shared__ float tl[64][65];
  int n0 = blockIdx.x * 64, c0 = blockIdx.y * 64, b = blockIdx.z;
  int tid = threadIdx.x;
  const float* S = sk + (size_t)b * CS * NS;
  int ni4 = (tid & 15) * 4, ci = tid >> 4;
  #pragma unroll
  for (int r = 0; r < 4; r++) {
    int cc = ci + 16 * r;
    float4 v = *(const float4*)(S + (size_t)(c0 + cc) * NS + n0 + ni4);
    tl[cc][ni4] = v.x; tl[cc][ni4 + 1] = v.y; tl[cc][ni4 + 2] = v.z; tl[cc][ni4 + 3] = v.w;
  }
  __syncthreads();
  ushort_t* O = x1 + (size_t)b * NS * CIN;
  int ci4 = (tid & 15) * 4, ni = tid >> 4;
  #pragma unroll
  for (int r = 0; r < 4; r++) {
    int nr = ni + 16 * r;
    ushort4 o;
    o.x = f2bf(tl[ci4 + 0][nr]); o.y = f2bf(tl[ci4 + 1][nr]);
    o.z = f2bf(tl[ci4 + 2][nr]); o.w = f2bf(tl[ci4 + 3][nr]);
    *(ushort4*)(O + (size_t)(n0 + nr) * CIN + CP + c0 + ci4) = o;
  }
}

// Interp: x1[b][n][0..255] = sum_k w3[k] * pptT[idx[k]][c].
__global__ __launch_bounds__(256) void interp_kernel(
    const ushort_t* __restrict__ pptT, const float* __restrict__ w3,
    const int* __restrict__ idx3, ushort_t* __restrict__ x1) {
  int tid = threadIdx.x;
  int nl = tid >> 6, l = tid & 63;
  int b = blockIdx.y;
  int n = blockIdx.x * 4 + nl;
  size_t nb = (size_t)b * NS + n;
  int j0 = idx3[nb * 3 + 0], j1 = idx3[nb * 3 + 1], j2 = idx3[nb * 3 + 2];
  float w0 = w3[nb * 3 + 0], w1 = w3[nb * 3 + 1], w2 = w3[nb * 3 + 2];
  const ushort_t* P = pptT + (size_t)b * NP * CP;
  int c = l * 4;
  ushort4 g0 = *(const ushort4*)(P + (size_t)j0 * CP + c);
  ushort4 g1 = *(const ushort4*)(P + (size_t)j1 * CP + c);
  ushort4 g2 = *(const ushort4*)(P + (size_t)j2 * CP + c);
  ushort4 o;
  o.x = f2bf(w0 * bf2f(g0.x) + w1 * bf2f(g1.x) + w2 * bf2f(g2.x));
  o.y = f2bf(w0 * bf2f(g0.y) + w1 * bf2f(g1.y) + w2 * bf2f(g2.y));
  o.z = f2bf(w0 * bf2f(g0.z) + w1 * bf2f(g1.z) + w2 * bf2f(g2.z));
  o.w = f2bf(w0 * bf2f(g0.w) + w1 * bf2f(g1.w) + w2 * bf2f(g2.w));
  *(ushort4*)(x1 + nb * CIN + c) = o;
}

// ---------------------------------------------------------------------------
// MFMA GEMM, BK=64, catalog 2-phase: double-buffered LDS (X,W), STAGE(t+1)
// issued BEFORE compute(t), ONE vmcnt+barrier per iteration (T3 minimum).
// XOR swizzle chunk^=(row&7), applied BOTH sides (rule #21).
// MODE 0: gemm1, X = x1 [b][n][384], pure global_load_lds staging.
// MODE 1: gemm2, X = relu(a1*y1+s1) reg-staged with 2-slot reg dbuf (loads
//         issued one iteration ahead; end-of-iter vmcnt(2) keeps them flying).
template <int MODE>
__global__ __launch_bounds__(256, 2) void gemm_bk64_kernel(
    const ushort_t* __restrict__ X, const ushort_t* __restrict__ Wb,
    ushort_t* __restrict__ Yb, float* __restrict__ stats,
    const float* __restrict__ stats_in, const float* __restrict__ g_in,
    const float* __restrict__ bt_in) {
  constexpr int KD = MODE ? CO : CIN;
  constexpr int NT = KD / 64;            // 4 or 6
  __shared__ __align__(16) char lds_raw[65536];  // X0 X1 W0 W1 (16K each)
  __shared__ float ssum[128], ssq[128];
  __shared__ float a1s[MODE ? CO : 1], s1s[MODE ? CO : 1];

  int tid = threadIdx.x;
  int w = tid >> 6, l = tid & 63;
  int bid = blockIdx.x;
  int by = (bid >> 3) & 1;
  int s = (bid & 7) + 8 * (bid >> 4);
  int bx = s & 31, bz = s >> 5;
  int n0 = bx * 128;
  if (tid < 128) { ssum[tid] = 0.f; ssq[tid] = 0.f; }
  if constexpr (MODE == 1) {
    float cnt = (float)NB * (float)NS;
    float m = stats_in[tid] / cnt;
    float var = stats_in[CO + tid] / cnt - m * m;
    var = fmaxf(var, 0.f);
    float invs = rsqrtf(var + 1e-5f);
    float av = g_in[tid] * invs;
    a1s[tid] = av; s1s[tid] = bt_in[tid] - m * av;
  }
  __syncthreads();

  // gload geometry: per wave 4 groups of 8 rows; lane l covers one 16B chunk.
  int grow = l >> 3;                 // 0..7
  int glc  = (l & 7) ^ grow;         // swizzled logical 16B chunk in 128B row
  // MODE1 reg-stage geometry
  int trow = tid >> 3;               // base row (0..31)
  int tlc  = (tid & 7) ^ (trow & 7); // logical chunk
  const ushort_t* Xb = X + (size_t)bz * NS * KD;

  auto ldsXp = [&](int buf) { return (ushort_t*)(lds_raw + buf * 16384); };
  auto ldsWp = [&](int buf) { return (ushort_t*)(lds_raw + 32768 + buf * 16384); };

  auto stageW = [&](int t, int buf) {
    int k0 = t * 64;
    ushort_t* dW = ldsWp(buf);
    #pragma unroll
    for (int i = 0; i < 4; i++) {
      int row = w * 32 + i * 8 + grow;
      gload16(Wb + (size_t)(by * 128 + row) * KD + k0 + glc * 8,
              &dW[(w * 32 + i * 8) * 64]);
    }
  };
  auto stageX0 = [&](int t, int buf) {   // MODE0: pure gload
    int k0 = t * 64;
    ushort_t* dX = ldsXp(buf);
    #pragma unroll
    for (int i = 0; i < 4; i++) {
      int row = w * 32 + i * 8 + grow;
      gload16(Xb + (size_t)(n0 + row) * KD + k0 + glc * 8,
              &dX[(w * 32 + i * 8) * 64]);
    }
  };

  us8 xr[2][4];                          // MODE1 reg slots (4 us8 each)
  auto issueXreg = [&](int t) {
    if constexpr (MODE == 1) {
      int k0 = t * 64, sl = t & 1;
      #pragma unroll
      for (int c = 0; c < 4; c++) {
        int row = trow + 32 * c;
        xr[sl][c] = *(const us8*)(Xb + (size_t)(n0 + row) * KD + k0 + tlc * 8);
      }
    }
  };
  auto writeact = [&](int t, int buf) {
    if constexpr (MODE == 1) {
      int k0 = t * 64, sl = t & 1;
      ushort_t* dX = ldsXp(buf);
      const float* ap = &a1s[k0 + tlc * 8];
      const float* sp = &s1s[k0 + tlc * 8];
      #pragma unroll
      for (int c = 0; c < 4; c++) {
        us8 v = xr[sl][c];
        us8 o;
        #pragma unroll
        for (int e = 0; e < 8; e++)
          o[e] = f2bf(fmaxf(fmaf(ap[e], bf2f(v[e]), sp[e]), 0.f));
        *(us8*)&dX[(tid + 256 * c) * 8] = o;
      }
    }
  };

  f32x4 acc[4][4];
  #pragma unroll
  for (int i = 0; i < 4; i++)
    #pragma unroll
    for (int j = 0; j < 4; j++) acc[i][j] = {0.f, 0.f, 0.f, 0.f};

  int wn = (w & 1) * 64, wo = (w >> 1) * 64;
  int lr = l & 15, lk = l >> 4;

  // ---- prologue
  if constexpr (MODE == 0) {
    stageW(0, 0); stageX0(0, 0);
    asm volatile("s_waitcnt vmcnt(0)" ::: "memory");
  } else {
    issueXreg(0);
    stageW(0, 0);
    issueXreg(1);
    writeact(0, 0);                       // implicit wait for xr(0)
    asm volatile("s_waitcnt vmcnt(2) lgkmcnt(0)" ::: "memory");  // W(0) landed
  }
  __builtin_amdgcn_s_barrier();
  __builtin_amdgcn_sched_barrier(0);

  int cur = 0;
  #pragma unroll
  for (int t = 0; t < NT; t++) {
    // ---- issue next-tile staging FIRST (hides under this tile's compute)
    if (t + 1 < NT) {
      stageW(t + 1, cur ^ 1);
      if constexpr (MODE == 0) stageX0(t + 1, cur ^ 1);
      else writeact(t + 1, cur ^ 1);      // waits xr(t+1), issued last iter
    }
    if constexpr (MODE == 1) { if (t + 2 < NT) issueXreg(t + 2); }
    // ---- compute tile t
    {
      const ushort_t* cX = ldsXp(cur);
      const ushort_t* cW = ldsWp(cur);
      #pragma unroll
      for (int ks = 0; ks < 2; ks++) {
        short8 af[4], bfr[4];
        #pragma unroll
        for (int i = 0; i < 4; i++) {
          int rr = wn + i * 16 + lr;
          int pc = (ks * 4 + lk) ^ (rr & 7);
          af[i] = *(const short8*)&cX[rr * 64 + pc * 8];
        }
        #pragma unroll
        for (int j = 0; j < 4; j++) {
          int rr = wo + j * 16 + lr;
          int pc = (ks * 4 + lk) ^ (rr & 7);
          bfr[j] = *(const short8*)&cW[rr * 64 + pc * 8];
        }
        asm volatile("s_waitcnt lgkmcnt(0)" ::: "memory");
        __builtin_amdgcn_sched_barrier(0);
        __builtin_amdgcn_s_setprio(1);
        #pragma unroll
        for (int i = 0; i < 4; i++)
          #pragma unroll
          for (int j = 0; j < 4; j++)
            acc[i][j] = __builtin_amdgcn_mfma_f32_16x16x32_bf16(af[i], bfr[j], acc[i][j], 0, 0, 0);
        __builtin_amdgcn_s_setprio(0);
      }
    }
    // ---- single wait+barrier: next tile's LDS landed; reads of cur done
    if (MODE == 1 && t + 2 < NT)
      asm volatile("s_waitcnt vmcnt(2) lgkmcnt(0)" ::: "memory");
    else
      asm volatile("s_waitcnt vmcnt(0) lgkmcnt(0)" ::: "memory");
    __builtin_amdgcn_s_barrier();
    __builtin_amdgcn_sched_barrier(0);
    cur ^= 1;
  }

  // ---- epilogue: BN stats from regs; tile -> LDS; coalesced row stores
  #pragma unroll
  for (int j = 0; j < 4; j++) {
    int ol = wo + j * 16 + lr;
    float ps = 0.f, pq = 0.f;
    #pragma unroll
    for (int i = 0; i < 4; i++)
      #pragma unroll
      for (int rg = 0; rg < 4; rg++) { float v = acc[i][j][rg]; ps += v; pq += v * v; }
    atomicAdd(&ssum[ol], ps);
    atomicAdd(&ssq[ol], pq);
  }
  ushort_t* lout = (ushort_t*)lds_raw;   // [128][132]
  #pragma unroll
  for (int i = 0; i < 4; i++)
    #pragma unroll
    for (int j = 0; j < 4; j++)
      #pragma unroll
      for (int rg = 0; rg < 4; rg++) {
        int nl = wn + i * 16 + lk * 4 + rg;
        int ol = wo + j * 16 + lr;
        lout[nl * 132 + ol] = f2bf(acc[i][j][rg]);
      }
  __syncthreads();
  {
    int row = tid >> 1, half = tid & 1;
    const ushort_t* src = lout + row * 132 + half * 64;
    ushort_t* dst = Yb + ((size_t)bz * NS + n0 + row) * CO + by * 128 + half * 64;
    #pragma unroll
    for (int k = 0; k < 8; k++)
      *(us8*)(dst + k * 8) = *(const us8*)(src + k * 8);
  }
  if (tid < 128) {
    atomicAdd(&stats[by * 128 + tid], ssum[tid]);
    atomicAdd(&stats[CO + by * 128 + tid], ssq[tid]);
  }
}

// Final BN2+ReLU with transpose, bf16 in [b][n][o] -> f32 out [b][o][n].
__global__ __launch_bounds__(256) void bnrelu_tr_kernel(
    const ushort_t* __restrict__ y2b, const float* __restrict__ stats_in,
    const float* __restrict__ g_in, const float* __restrict__ bt_in,
    float* __restrict__ out) {
  __shared__ float tl[64][65];
  __shared__ float a2s[64], s2s[64];
  int n0 = blockIdx.x * 64, o0 = blockIdx.y * 64, b = blockIdx.z;
  const ushort_t* Y = y2b + (size_t)b * NS * CO;
  int tid = threadIdx.x;
  if (tid < 64) {
    int o = o0 + tid;
    float cnt = (float)NB * (float)NS;
    float m = stats_in[o] / cnt;
    float var = stats_in[CO + o] / cnt - m * m;
    var = fmaxf(var, 0.f);
    float invs = rsqrtf(var + 1e-5f);
    float av = g_in[o] * invs;
    a2s[tid] = av; s2s[tid] = bt_in[o] - m * av;
  }
  int o8 = (tid & 7) * 8, row = tid >> 3;
  #pragma unroll
  for (int r = 0; r < 2; r++) {
    int ii = row + 32 * r;
    const ushort_t* src = Y + (size_t)(n0 + ii) * CO + o0 + o8;
    ushort4 v0 = *(const ushort4*)(src);
    ushort4 v1 = *(const ushort4*)(src + 4);
    tl[ii][o8 + 0] = bf2f(v0.x); tl[ii][o8 + 1] = bf2f(v0.y);
    tl[ii][o8 + 2] = bf2f(v0.z); tl[ii][o8 + 3] = bf2f(v0.w);
    tl[ii][o8 + 4] = bf2f(v1.x); tl[ii][o8 + 5] = bf2f(v1.y);
    tl[ii][o8 + 6] = bf2f(v1.z); tl[ii][o8 + 7] = bf2f(v1.w);
  }
  __syncthreads();
  float* O = out + (size_t)b * CO * NS;
  int ii4 = (tid & 15) * 4, j = tid >> 4;
  #pragma unroll
  for (int r = 0; r < 4; r++) {
    int jj = j + 16 * r;
    float av = a2s[jj], sv = s2s[jj];
    float4 v;
    v.x = fmaxf(fmaf(av, tl[ii4 + 0][jj], sv), 0.f);
    v.y = fmaxf(fmaf(av, tl[ii4 + 1][jj], sv), 0.f);
    v.z = fmaxf(fmaf(av, tl[ii4 + 2][jj], sv), 0.f);
    v.w = fmaxf(fmaf(av, tl[ii4 + 3][jj], sv), 0.f);
    *(float4*)(O + (size_t)(o0 + jj) * NS + n0 + ii4) = v;
  }
}

extern "C" void kernel_launch(void* const* d_in, const int* in_sizes, int n_in,
                              void* d_out, int out_size, void* d_ws, size_t ws_size,
                              hipStream_t stream) {
  const float* xyz_prev    = (const float*)d_in[0];
  const float* xyz_skip    = (const float*)d_in[1];
  const float* points_prev = (const float*)d_in[2];
  const float* points_skip = (const float*)d_in[3];
  const float* W1 = (const float*)d_in[4];
  const float* g1 = (const float*)d_in[5];
  const float* b1 = (const float*)d_in[6];
  const float* W2 = (const float*)d_in[7];
  const float* g2 = (const float*)d_in[8];
  const float* b2 = (const float*)d_in[9];
  float* out = (float*)d_out;

  // workspace layout (256B-aligned sequential allocs)
  char* W = (char*)d_ws;
  size_t off = 0;
  auto alloc = [&](size_t bytes) {
    size_t o = off; off = (off + bytes + 255) & ~(size_t)255; return o;
  };
  ushort_t* x1   = (ushort_t*)(W + alloc((size_t)NB * NS * CIN * 2));  // 50.3MB
  ushort_t* y1b  = (ushort_t*)(W + alloc((size_t)NB * NS * CO * 2));   // 33.6MB
  ushort_t* pptT = (ushort_t*)(W + alloc((size_t)NB * NP * CP * 2));   // 8.4MB
  ushort_t* W1b  = (ushort_t*)(W + alloc((size_t)CO * CIN * 2));
  ushort_t* W2b  = (ushort_t*)(W + alloc((size_t)CO * CO * 2));
  float* w3   = (float*)(W + alloc((size_t)NB * NS * 3 * 4));
  int*   idx3 = (int*)(W + alloc((size_t)NB * NS * 3 * 4));
  float* st1  = (float*)(W + alloc(512 * 4));
  float* st2  = (float*)(W + alloc(512 * 4));
  size_t y2_off = alloc((size_t)NB * NS * CO * 2);                     // 33.6MB bf16
  bool full = (ws_size >= off);
  ushort_t* y2b = full ? (ushort_t*)(W + y2_off) : (ushort_t*)d_out;
  // pbuf (16.8MB, transient, consumed before any y2 write) aliases y2 region
  float* pbuf = full ? (float*)(W + y2_off) : (float*)d_out;

  hipLaunchKernelGGL(topk_chunk_kernel, dim3(NS / 512, NCHUNK, NB), dim3(256), 0,
                     stream, xyz_prev, xyz_skip, pbuf);
  hipLaunchKernelGGL(topk_merge_kernel, dim3(NB * NS / 256), dim3(256), 0, stream,
                     pbuf, w3, idx3);
  hipLaunchKernelGGL(wcast_kernel, dim3((CO * CIN / 4 + CO * CO / 4 + 255) / 256),
                     dim3(256), 0, stream, W1, W2, W1b, W2b, st1, st2);
  hipLaunchKernelGGL(ppT_kernel, dim3(NP / 64, CP / 64, NB), dim3(256), 0, stream,
                     points_prev, pptT);
  hipLaunchKernelGGL(skipT_kernel, dim3(NS / 64, CS / 64, NB), dim3(256), 0, stream,
                     points_skip, x1);
  hipLaunchKernelGGL(interp_kernel, dim3(NS / 4, NB), dim3(256), 0, stream,
                     pptT, w3, idx3, x1);
  hipLaunchKernelGGL((gemm_bk64_kernel<0>), dim3(1024), dim3(256), 0, stream,
                     x1, W1b, y1b, st1, (const float*)nullptr,
                     (const float*)nullptr, (const float*)nullptr);
  hipLaunchKernelGGL((gemm_bk64_kernel<1>), dim3(1024), dim3(256), 0, stream,
                     y1b, W2b, y2b, st2, st1, g1, b1);
  if (full) {
    hipLaunchKernelGGL(bnrelu_tr_kernel, dim3(NS / 64, CO / 64, NB), dim3(256), 0,
                       stream, y2b, st2, g2, b2, out);
  } else {
    float* stage = (float*)d_ws;
    hipLaunchKernelGGL(bnrelu_tr_kernel, dim3(NS / 64, CO / 64, NB), dim3(256), 0,
                       stream, y2b, st2, g2, b2, stage);
    hipMemcpyAsync(out, stage, (size_t)NB * NS * CO * 4, hipMemcpyDeviceToDevice,
                   stream);
  }
}

// Round 11
// 162.061 us; speedup vs baseline: 1.0233x; 1.0072x over previous
//
#include <hip/hip_runtime.h>
#include <math.h>

// Problem dims (fixed by the reference)
constexpr int NB  = 16;    // batch
constexpr int NP  = 1024;  // prev points
constexpr int NS  = 4096;  // skip points
constexpr int CP  = 256;   // prev channels
constexpr int CS  = 128;   // skip channels
constexpr int CIN = 384;   // CP + CS
constexpr int CO  = 256;   // output channels

constexpr int NCHUNK = 16;          // prev-point chunks for topk parallelism
constexpr int CHPTS  = NP / NCHUNK; // 64

typedef unsigned int uint;
typedef unsigned short ushort_t;
typedef __attribute__((ext_vector_type(8))) short short8;
typedef __attribute__((ext_vector_type(8))) unsigned short us8;
typedef __attribute__((ext_vector_type(4))) float f32x4;

__device__ __forceinline__ ushort_t f2bf(float f) {
  uint u = __float_as_uint(f);
  uint r = (u + 0x7fffu + ((u >> 16) & 1u)) >> 16;   // RNE
  return (ushort_t)r;
}
__device__ __forceinline__ float bf2f(ushort_t u) {
  return __uint_as_float(((uint)u) << 16);
}

__device__ __forceinline__ void gload16(const void* g, void* l) {
  __builtin_amdgcn_global_load_lds(
      (const __attribute__((address_space(1))) uint*)g,
      (__attribute__((address_space(3))) uint*)l, 16, 0, 0);
}

// Packed-key top-3 step (set-level correctness; masked-dist err <= 2^-13 rel).
__device__ __forceinline__ void tkp(float pxv, float pyv, float pzv, int pi,
                                    float qx, float qy, float qz,
                                    float& k0, float& k1, float& k2,
                                    float& rsum) {
  float dx = pxv - qx, dy = pyv - qy, dz = pzv - qz;
  float sq = fmaf(dz, dz, fmaf(dy, dy, fmaf(dx, dx, 1e-16f)));
  rsum += __builtin_amdgcn_rsqf(sq);
  float k = __uint_as_float((__float_as_uint(sq) & 0xFFFFFC00u) | (uint)pi);
  k2 = __builtin_amdgcn_fmed3f(k1, k2, k);
  k1 = __builtin_amdgcn_fmed3f(k0, k1, k);
  k0 = fminf(k0, k);
}

// ---------------------------------------------------------------------------
// topk stage 1 (unchanged)
__global__ __launch_bounds__(256) void topk_chunk_kernel(
    const float* __restrict__ xyz_prev, const float* __restrict__ xyz_skip,
    float* __restrict__ pbuf) {
  __shared__ float px[CHPTS], py[CHPTS], pz[CHPTS];
  int q  = blockIdx.y;
  int b  = blockIdx.z;
  int tid = threadIdx.x;
  if (tid < CHPTS) {
    const float* xp = xyz_prev + ((size_t)b * NP + q * CHPTS + tid) * 3;
    px[tid] = xp[0]; py[tid] = xp[1]; pz[tid] = xp[2];
  }
  __syncthreads();
  int nA = blockIdx.x * 512 + tid;
  int nB = nA + 256;
  const float* xqA = xyz_skip + ((size_t)b * NS + nA) * 3;
  const float* xqB = xyz_skip + ((size_t)b * NS + nB) * 3;
  float qxA = xqA[0], qyA = xqA[1], qzA = xqA[2];
  float qxB = xqB[0], qyB = xqB[1], qzB = xqB[2];
  float kA0 = INFINITY, kA1 = INFINITY, kA2 = INFINITY;
  float kB0 = INFINITY, kB1 = INFINITY, kB2 = INFINITY;
  float rsA = 0.f, rsB = 0.f;
  int pbase = q * CHPTS;
  for (int p = 0; p < CHPTS; p += 4) {
    float4 X = *(const float4*)&px[p];
    float4 Y = *(const float4*)&py[p];
    float4 Z = *(const float4*)&pz[p];
    tkp(X.x, Y.x, Z.x, pbase + p + 0, qxA, qyA, qzA, kA0, kA1, kA2, rsA);
    tkp(X.x, Y.x, Z.x, pbase + p + 0, qxB, qyB, qzB, kB0, kB1, kB2, rsB);
    tkp(X.y, Y.y, Z.y, pbase + p + 1, qxA, qyA, qzA, kA0, kA1, kA2, rsA);
    tkp(X.y, Y.y, Z.y, pbase + p + 1, qxB, qyB, qzB, kB0, kB1, kB2, rsB);
    tkp(X.z, Y.z, Z.z, pbase + p + 2, qxA, qyA, qzA, kA0, kA1, kA2, rsA);
    tkp(X.z, Y.z, Z.z, pbase + p + 2, qxB, qyB, qzB, kB0, kB1, kB2, rsB);
    tkp(X.w, Y.w, Z.w, pbase + p + 3, qxA, qyA, qzA, kA0, kA1, kA2, rsA);
    tkp(X.w, Y.w, Z.w, pbase + p + 3, qxB, qyB, qzB, kB0, kB1, kB2, rsB);
  }
  size_t PA = ((size_t)(b * NCHUNK + q) * NS + nA) * 4;
  size_t PB = ((size_t)(b * NCHUNK + q) * NS + nB) * 4;
  *(float4*)(pbuf + PA) = make_float4(kA0, kA1, kA2, rsA);
  *(float4*)(pbuf + PB) = make_float4(kB0, kB1, kB2, rsB);
}

// topk stage 2 (unchanged)
__global__ __launch_bounds__(256) void topk_merge_kernel(
    const float* __restrict__ pbuf, float* __restrict__ w3,
    int* __restrict__ idx3) {
  int gid = blockIdx.x * 256 + threadIdx.x;  // = b*NS + n
  int b = gid >> 12;
  int n = gid & (NS - 1);
  float k0 = INFINITY, k1 = INFINITY, k2 = INFINITY;
  float rsum = 0.f;
  #pragma unroll 4
  for (int q = 0; q < NCHUNK; q++) {
    float4 v = *(const float4*)(pbuf + ((size_t)(b * NCHUNK + q) * NS + n) * 4);
    rsum += v.w;
    k2 = __builtin_amdgcn_fmed3f(k1, k2, v.x);
    k1 = __builtin_amdgcn_fmed3f(k0, k1, v.x);
    k0 = fminf(k0, v.x);
    k2 = __builtin_amdgcn_fmed3f(k1, k2, v.y);
    k1 = __builtin_amdgcn_fmed3f(k0, k1, v.y);
    k0 = fminf(k0, v.y);
    k2 = __builtin_amdgcn_fmed3f(k1, k2, v.z);
    k1 = __builtin_amdgcn_fmed3f(k0, k1, v.z);
    k0 = fminf(k0, v.z);
  }
  float inv = 1.0f / rsum;
  uint u0 = __float_as_uint(k0), u1 = __float_as_uint(k1), u2 = __float_as_uint(k2);
  float d0 = __uint_as_float(u0 & 0xFFFFFC00u);
  float d1 = __uint_as_float(u1 & 0xFFFFFC00u);
  float d2 = __uint_as_float(u2 & 0xFFFFFC00u);
  size_t base = (size_t)gid * 3;
  w3[base + 0] = __builtin_amdgcn_rsqf(d0) * inv;
  w3[base + 1] = __builtin_amdgcn_rsqf(d1) * inv;
  w3[base + 2] = __builtin_amdgcn_rsqf(d2) * inv;
  idx3[base + 0] = (int)(u0 & 1023u);
  idx3[base + 1] = (int)(u1 & 1023u);
  idx3[base + 2] = (int)(u2 & 1023u);
}

// ---------------------------------------------------------------------------
// W fp32 -> bf16; block 0 also zeros the BN stats accumulators.
__global__ __launch_bounds__(256) void wcast_kernel(
    const float* __restrict__ W1, const float* __restrict__ W2,
    ushort_t* __restrict__ W1b, ushort_t* __restrict__ W2b,
    float* __restrict__ st1, float* __restrict__ st2) {
  int tid = threadIdx.x;
  if (blockIdx.x == 0) {
    st1[tid] = 0.f; st1[tid + 256] = 0.f;
    st2[tid] = 0.f; st2[tid + 256] = 0.f;
  }
  int t = blockIdx.x * 256 + tid;
  int n1 = CO * CIN / 4;
  if (t < n1) {
    float4 v = *(const float4*)(W1 + t * 4);
    ushort4 o; o.x = f2bf(v.x); o.y = f2bf(v.y); o.z = f2bf(v.z); o.w = f2bf(v.w);
    *(ushort4*)(W1b + t * 4) = o;
  } else {
    int u = t - n1;
    float4 v = *(const float4*)(W2 + u * 4);
    ushort4 o; o.x = f2bf(v.x); o.y = f2bf(v.y); o.z = f2bf(v.z); o.w = f2bf(v.w);
    *(ushort4*)(W2b + u * 4) = o;
  }
}

// ---------------------------------------------------------------------------
// Transpose points_prev [b][256][1024] f32 -> pptT [b][1024][256] bf16.
__global__ __launch_bounds__(256) void ppT_kernel(
    const float* __restrict__ pp, ushort_t* __restrict__ pptT) {
  __shared__ float tl[64][65];
  int p0 = blockIdx.x * 64, c0 = blockIdx.y * 64, b = blockIdx.z;
  int tid = threadIdx.x;
  const float* P = pp + (size_t)b * CP * NP;
  int pi4 = (tid & 15) * 4, ci = tid >> 4;
  #pragma unroll
  for (int r = 0; r < 4; r++) {
    int cc = ci + 16 * r;
    float4 v = *(const float4*)(P + (size_t)(c0 + cc) * NP + p0 + pi4);
    tl[cc][pi4] = v.x; tl[cc][pi4 + 1] = v.y; tl[cc][pi4 + 2] = v.z; tl[cc][pi4 + 3] = v.w;
  }
  __syncthreads();
  ushort_t* O = pptT + (size_t)b * NP * CP;
  int ci4 = (tid & 15) * 4, pi = tid >> 4;
  #pragma unroll
  for (int r = 0; r < 4; r++) {
    int pr = pi + 16 * r;
    ushort4 o;
    o.x = f2bf(tl[ci4 + 0][pr]); o.y = f2bf(tl[ci4 + 1][pr]);
    o.z = f2bf(tl[ci4 + 2][pr]); o.w = f2bf(tl[ci4 + 3][pr]);
    *(ushort4*)(O + (size_t)(p0 + pr) * CP + c0 + ci4) = o;
  }
}

// Transpose points_skip [b][128][4096] f32 -> x1[b][n][256..383] bf16.
__global__ __launch_bounds__(256) void skipT_kernel(
    const float* __restrict__ sk, ushort_t* __restrict__ x1) {
  __shared__ float tl[64][65];
  int n0 = blockIdx.x * 64, c0 = blockIdx.y * 64, b = blockIdx.z;
  int tid = threadIdx.x;
  const float* S = sk + (size_t)b * CS * NS;
  int ni4 = (tid & 15) * 4, ci = tid >> 4;
  #pragma unroll
  for (int r = 0; r < 4; r++) {
    int cc = ci + 16 * r;
    float4 v = *(const float4*)(S + (size_t)(c0 + cc) * NS + n0 + ni4);
    tl[cc][ni4] = v.x; tl[cc][ni4 + 1] = v.y; tl[cc][ni4 + 2] = v.z; tl[cc][ni4 + 3] = v.w;
  }
  __syncthreads();
  ushort_t* O = x1 + (size_t)b * NS * CIN;
  int ci4 = (tid & 15) * 4, ni = tid >> 4;
  #pragma unroll
  for (int r = 0; r < 4; r++) {
    int nr = ni + 16 * r;
    ushort4 o;
    o.x = f2bf(tl[ci4 + 0][nr]); o.y = f2bf(tl[ci4 + 1][nr]);
    o.z = f2bf(tl[ci4 + 2][nr]); o.w = f2bf(tl[ci4 + 3][nr]);
    *(ushort4*)(O + (size_t)(n0 + nr) * CIN + CP + c0 + ci4) = o;
  }
}

// Interp: x1[b][n][0..255] = sum_k w3[k] * pptT[idx[k]][c].
__global__ __launch_bounds__(256) void interp_kernel(
    const ushort_t* __restrict__ pptT, const float* __restrict__ w3,
    const int* __restrict__ idx3, ushort_t* __restrict__ x1) {
  int tid = threadIdx.x;
  int nl = tid >> 6, l = tid & 63;
  int b = blockIdx.y;
  int n = blockIdx.x * 4 + nl;
  size_t nb = (size_t)b * NS + n;
  int j0 = idx3[nb * 3 + 0], j1 = idx3[nb * 3 + 1], j2 = idx3[nb * 3 + 2];
  float w0 = w3[nb * 3 + 0], w1 = w3[nb * 3 + 1], w2 = w3[nb * 3 + 2];
  const ushort_t* P = pptT + (size_t)b * NP * CP;
  int c = l * 4;
  ushort4 g0 = *(const ushort4*)(P + (size_t)j0 * CP + c);
  ushort4 g1 = *(const ushort4*)(P + (size_t)j1 * CP + c);
  ushort4 g2 = *(const ushort4*)(P + (size_t)j2 * CP + c);
  ushort4 o;
  o.x = f2bf(w0 * bf2f(g0.x) + w1 * bf2f(g1.x) + w2 * bf2f(g2.x));
  o.y = f2bf(w0 * bf2f(g0.y) + w1 * bf2f(g1.y) + w2 * bf2f(g2.y));
  o.z = f2bf(w0 * bf2f(g0.z) + w1 * bf2f(g1.z) + w2 * bf2f(g2.z));
  o.w = f2bf(w0 * bf2f(g0.w) + w1 * bf2f(g1.w) + w2 * bf2f(g2.w));
  *(ushort4*)(x1 + nb * CIN + c) = o;
}

// ---------------------------------------------------------------------------
// Stats partial reducer: pstat [1024][256] ([0..127]=sum, [128..255]=sq per
// block for its by-half) -> stats[512] (sum[256], sq[256]).
// grid 32 x 256; coalesced column sums; low-contention atomics (32/addr).
__global__ __launch_bounds__(256) void statreduce_kernel(
    const float* __restrict__ pstat, float* __restrict__ stats) {
  int t = threadIdx.x;
  int r0 = blockIdx.x * 32;
  float A0 = 0.f, A1 = 0.f;
  #pragma unroll
  for (int i = 0; i < 32; i++) {
    float v = pstat[(size_t)(r0 + i) * 256 + t];
    if (((i >> 3) & 1) == 0) A0 += v; else A1 += v;   // by = (bid>>3)&1
  }
  // class0 -> channels 0..127; class1 -> channels 128..255
  if (t < 128) {
    atomicAdd(&stats[t], A0);            // sum ch t
    atomicAdd(&stats[128 + t], A1);      // sum ch 128+t
  } else {
    int c = t - 128;
    atomicAdd(&stats[256 + c], A0);      // sq ch c
    atomicAdd(&stats[256 + 128 + c], A1);// sq ch 128+c
  }
}

// ---------------------------------------------------------------------------
// MFMA GEMM, BK=64, catalog 2-phase double-buffered (identical to round 10)
// EXCEPT: BN stats written as per-block partials (no global atomics).
template <int MODE>
__global__ __launch_bounds__(256, 2) void gemm_bk64_kernel(
    const ushort_t* __restrict__ X, const ushort_t* __restrict__ Wb,
    ushort_t* __restrict__ Yb, float* __restrict__ pstat,
    const float* __restrict__ stats_in, const float* __restrict__ g_in,
    const float* __restrict__ bt_in) {
  constexpr int KD = MODE ? CO : CIN;
  constexpr int NT = KD / 64;            // 4 or 6
  __shared__ __align__(16) char lds_raw[65536];  // X0 X1 W0 W1 (16K each)
  __shared__ float ssum[128], ssq[128];
  __shared__ float a1s[MODE ? CO : 1], s1s[MODE ? CO : 1];

  int tid = threadIdx.x;
  int w = tid >> 6, l = tid & 63;
  int bid = blockIdx.x;
  int by = (bid >> 3) & 1;
  int s = (bid & 7) + 8 * (bid >> 4);
  int bx = s & 31, bz = s >> 5;
  int n0 = bx * 128;
  if (tid < 128) { ssum[tid] = 0.f; ssq[tid] = 0.f; }
  if constexpr (MODE == 1) {
    float cnt = (float)NB * (float)NS;
    float m = stats_in[tid] / cnt;
    float var = stats_in[CO + tid] / cnt - m * m;
    var = fmaxf(var, 0.f);
    float invs = rsqrtf(var + 1e-5f);
    float av = g_in[tid] * invs;
    a1s[tid] = av; s1s[tid] = bt_in[tid] - m * av;
  }
  __syncthreads();

  int grow = l >> 3;
  int glc  = (l & 7) ^ grow;
  int trow = tid >> 3;
  int tlc  = (tid & 7) ^ (trow & 7);
  const ushort_t* Xb = X + (size_t)bz * NS * KD;

  auto ldsXp = [&](int buf) { return (ushort_t*)(lds_raw + buf * 16384); };
  auto ldsWp = [&](int buf) { return (ushort_t*)(lds_raw + 32768 + buf * 16384); };

  auto stageW = [&](int t, int buf) {
    int k0 = t * 64;
    ushort_t* dW = ldsWp(buf);
    #pragma unroll
    for (int i = 0; i < 4; i++) {
      int row = w * 32 + i * 8 + grow;
      gload16(Wb + (size_t)(by * 128 + row) * KD + k0 + glc * 8,
              &dW[(w * 32 + i * 8) * 64]);
    }
  };
  auto stageX0 = [&](int t, int buf) {
    int k0 = t * 64;
    ushort_t* dX = ldsXp(buf);
    #pragma unroll
    for (int i = 0; i < 4; i++) {
      int row = w * 32 + i * 8 + grow;
      gload16(Xb + (size_t)(n0 + row) * KD + k0 + glc * 8,
              &dX[(w * 32 + i * 8) * 64]);
    }
  };

  us8 xr[2][4];
  auto issueXreg = [&](int t) {
    if constexpr (MODE == 1) {
      int k0 = t * 64, sl = t & 1;
      #pragma unroll
      for (int c = 0; c < 4; c++) {
        int row = trow + 32 * c;
        xr[sl][c] = *(const us8*)(Xb + (size_t)(n0 + row) * KD + k0 + tlc * 8);
      }
    }
  };
  auto writeact = [&](int t, int buf) {
    if constexpr (MODE == 1) {
      int k0 = t * 64, sl = t & 1;
      ushort_t* dX = ldsXp(buf);
      const float* ap = &a1s[k0 + tlc * 8];
      const float* sp = &s1s[k0 + tlc * 8];
      #pragma unroll
      for (int c = 0; c < 4; c++) {
        us8 v = xr[sl][c];
        us8 o;
        #pragma unroll
        for (int e = 0; e < 8; e++)
          o[e] = f2bf(fmaxf(fmaf(ap[e], bf2f(v[e]), sp[e]), 0.f));
        *(us8*)&dX[(tid + 256 * c) * 8] = o;
      }
    }
  };

  f32x4 acc[4][4];
  #pragma unroll
  for (int i = 0; i < 4; i++)
    #pragma unroll
    for (int j = 0; j < 4; j++) acc[i][j] = {0.f, 0.f, 0.f, 0.f};

  int wn = (w & 1) * 64, wo = (w >> 1) * 64;
  int lr = l & 15, lk = l >> 4;

  // ---- prologue
  if constexpr (MODE == 0) {
    stageW(0, 0); stageX0(0, 0);
    asm volatile("s_waitcnt vmcnt(0)" ::: "memory");
  } else {
    issueXreg(0);
    stageW(0, 0);
    issueXreg(1);
    writeact(0, 0);
    asm volatile("s_waitcnt vmcnt(2) lgkmcnt(0)" ::: "memory");
  }
  __builtin_amdgcn_s_barrier();
  __builtin_amdgcn_sched_barrier(0);

  int cur = 0;
  #pragma unroll
  for (int t = 0; t < NT; t++) {
    if (t + 1 < NT) {
      stageW(t + 1, cur ^ 1);
      if constexpr (MODE == 0) stageX0(t + 1, cur ^ 1);
      else writeact(t + 1, cur ^ 1);
    }
    if constexpr (MODE == 1) { if (t + 2 < NT) issueXreg(t + 2); }
    {
      const ushort_t* cX = ldsXp(cur);
      const ushort_t* cW = ldsWp(cur);
      #pragma unroll
      for (int ks = 0; ks < 2; ks++) {
        short8 af[4], bfr[4];
        #pragma unroll
        for (int i = 0; i < 4; i++) {
          int rr = wn + i * 16 + lr;
          int pc = (ks * 4 + lk) ^ (rr & 7);
          af[i] = *(const short8*)&cX[rr * 64 + pc * 8];
        }
        #pragma unroll
        for (int j = 0; j < 4; j++) {
          int rr = wo + j * 16 + lr;
          int pc = (ks * 4 + lk) ^ (rr & 7);
          bfr[j] = *(const short8*)&cW[rr * 64 + pc * 8];
        }
        asm volatile("s_waitcnt lgkmcnt(0)" ::: "memory");
        __builtin_amdgcn_sched_barrier(0);
        __builtin_amdgcn_s_setprio(1);
        #pragma unroll
        for (int i = 0; i < 4; i++)
          #pragma unroll
          for (int j = 0; j < 4; j++)
            acc[i][j] = __builtin_amdgcn_mfma_f32_16x16x32_bf16(af[i], bfr[j], acc[i][j], 0, 0, 0);
        __builtin_amdgcn_s_setprio(0);
      }
    }
    if (MODE == 1 && t + 2 < NT)
      asm volatile("s_waitcnt vmcnt(2) lgkmcnt(0)" ::: "memory");
    else
      asm volatile("s_waitcnt vmcnt(0) lgkmcnt(0)" ::: "memory");
    __builtin_amdgcn_s_barrier();
    __builtin_amdgcn_sched_barrier(0);
    cur ^= 1;
  }

  // ---- epilogue: BN stats partials (NO global atomics); coalesced C write
  #pragma unroll
  for (int j = 0; j < 4; j++) {
    int ol = wo + j * 16 + lr;
    float ps = 0.f, pq = 0.f;
    #pragma unroll
    for (int i = 0; i < 4; i++)
      #pragma unroll
      for (int rg = 0; rg < 4; rg++) { float v = acc[i][j][rg]; ps += v; pq += v * v; }
    atomicAdd(&ssum[ol], ps);
    atomicAdd(&ssq[ol], pq);
  }
  ushort_t* lout = (ushort_t*)lds_raw;   // [128][132]
  #pragma unroll
  for (int i = 0; i < 4; i++)
    #pragma unroll
    for (int j = 0; j < 4; j++)
      #pragma unroll
      for (int rg = 0; rg < 4; rg++) {
        int nl = wn + i * 16 + lk * 4 + rg;
        int ol = wo + j * 16 + lr;
        lout[nl * 132 + ol] = f2bf(acc[i][j][rg]);
      }
  __syncthreads();
  {
    int row = tid >> 1, half = tid & 1;
    const ushort_t* src = lout + row * 132 + half * 64;
    ushort_t* dst = Yb + ((size_t)bz * NS + n0 + row) * CO + by * 128 + half * 64;
    #pragma unroll
    for (int k = 0; k < 8; k++)
      *(us8*)(dst + k * 8) = *(const us8*)(src + k * 8);
  }
  if (tid < 128) {
    float* ps = pstat + (size_t)bid * 256;
    ps[tid] = ssum[tid];
    ps[128 + tid] = ssq[tid];
  }
}

// Final BN2+ReLU with transpose, bf16 in [b][n][o] -> f32 out [b][o][n].
__global__ __launch_bounds__(256) void bnrelu_tr_kernel(
    const ushort_t* __restrict__ y2b, const float* __restrict__ stats_in,
    const float* __restrict__ g_in, const float* __restrict__ bt_in,
    float* __restrict__ out) {
  __shared__ float tl[64][65];
  __shared__ float a2s[64], s2s[64];
  int n0 = blockIdx.x * 64, o0 = blockIdx.y * 64, b = blockIdx.z;
  const ushort_t* Y = y2b + (size_t)b * NS * CO;
  int tid = threadIdx.x;
  if (tid < 64) {
    int o = o0 + tid;
    float cnt = (float)NB * (float)NS;
    float m = stats_in[o] / cnt;
    float var = stats_in[CO + o] / cnt - m * m;
    var = fmaxf(var, 0.f);
    float invs = rsqrtf(var + 1e-5f);
    float av = g_in[o] * invs;
    a2s[tid] = av; s2s[tid] = bt_in[o] - m * av;
  }
  int o8 = (tid & 7) * 8, row = tid >> 3;
  #pragma unroll
  for (int r = 0; r < 2; r++) {
    int ii = row + 32 * r;
    const ushort_t* src = Y + (size_t)(n0 + ii) * CO + o0 + o8;
    ushort4 v0 = *(const ushort4*)(src);
    ushort4 v1 = *(const ushort4*)(src + 4);
    tl[ii][o8 + 0] = bf2f(v0.x); tl[ii][o8 + 1] = bf2f(v0.y);
    tl[ii][o8 + 2] = bf2f(v0.z); tl[ii][o8 + 3] = bf2f(v0.w);
    tl[ii][o8 + 4] = bf2f(v1.x); tl[ii][o8 + 5] = bf2f(v1.y);
    tl[ii][o8 + 6] = bf2f(v1.z); tl[ii][o8 + 7] = bf2f(v1.w);
  }
  __syncthreads();
  float* O = out + (size_t)b * CO * NS;
  int ii4 = (tid & 15) * 4, j = tid >> 4;
  #pragma unroll
  for (int r = 0; r < 4; r++) {
    int jj = j + 16 * r;
    float av = a2s[jj], sv = s2s[jj];
    float4 v;
    v.x = fmaxf(fmaf(av, tl[ii4 + 0][jj], sv), 0.f);
    v.y = fmaxf(fmaf(av, tl[ii4 + 1][jj], sv), 0.f);
    v.z = fmaxf(fmaf(av, tl[ii4 + 2][jj], sv), 0.f);
    v.w = fmaxf(fmaf(av, tl[ii4 + 3][jj], sv), 0.f);
    *(float4*)(O + (size_t)(o0 + jj) * NS + n0 + ii4) = v;
  }
}

extern "C" void kernel_launch(void* const* d_in, const int* in_sizes, int n_in,
                              void* d_out, int out_size, void* d_ws, size_t ws_size,
                              hipStream_t stream) {
  const float* xyz_prev    = (const float*)d_in[0];
  const float* xyz_skip    = (const float*)d_in[1];
  const float* points_prev = (const float*)d_in[2];
  const float* points_skip = (const float*)d_in[3];
  const float* W1 = (const float*)d_in[4];
  const float* g1 = (const float*)d_in[5];
  const float* b1 = (const float*)d_in[6];
  const float* W2 = (const float*)d_in[7];
  const float* g2 = (const float*)d_in[8];
  const float* b2 = (const float*)d_in[9];
  float* out = (float*)d_out;

  // workspace layout (256B-aligned sequential allocs)
  char* W = (char*)d_ws;
  size_t off = 0;
  auto alloc = [&](size_t bytes) {
    size_t o = off; off = (off + bytes + 255) & ~(size_t)255; return o;
  };
  ushort_t* x1   = (ushort_t*)(W + alloc((size_t)NB * NS * CIN * 2));  // 50.3MB
  ushort_t* y1b  = (ushort_t*)(W + alloc((size_t)NB * NS * CO * 2));   // 33.6MB
  ushort_t* pptT = (ushort_t*)(W + alloc((size_t)NB * NP * CP * 2));   // 8.4MB
  ushort_t* W1b  = (ushort_t*)(W + alloc((size_t)CO * CIN * 2));
  ushort_t* W2b  = (ushort_t*)(W + alloc((size_t)CO * CO * 2));
  float* w3   = (float*)(W + alloc((size_t)NB * NS * 3 * 4));
  int*   idx3 = (int*)(W + alloc((size_t)NB * NS * 3 * 4));
  float* st1  = (float*)(W + alloc(512 * 4));
  float* st2  = (float*)(W + alloc(512 * 4));
  float* pst1 = (float*)(W + alloc(1024 * 256 * 4));                   // 1MB
  float* pst2 = (float*)(W + alloc(1024 * 256 * 4));                   // 1MB
  size_t y2_off = alloc((size_t)NB * NS * CO * 2);                     // 33.6MB bf16
  bool full = (ws_size >= off);
  ushort_t* y2b = full ? (ushort_t*)(W + y2_off) : (ushort_t*)d_out;
  // pbuf (16.8MB, transient, consumed before any y2 write) aliases y2 region
  float* pbuf = full ? (float*)(W + y2_off) : (float*)d_out;

  hipLaunchKernelGGL(topk_chunk_kernel, dim3(NS / 512, NCHUNK, NB), dim3(256), 0,
                     stream, xyz_prev, xyz_skip, pbuf);
  hipLaunchKernelGGL(topk_merge_kernel, dim3(NB * NS / 256), dim3(256), 0, stream,
                     pbuf, w3, idx3);
  hipLaunchKernelGGL(wcast_kernel, dim3((CO * CIN / 4 + CO * CO / 4 + 255) / 256),
                     dim3(256), 0, stream, W1, W2, W1b, W2b, st1, st2);
  hipLaunchKernelGGL(ppT_kernel, dim3(NP / 64, CP / 64, NB), dim3(256), 0, stream,
                     points_prev, pptT);
  hipLaunchKernelGGL(skipT_kernel, dim3(NS / 64, CS / 64, NB), dim3(256), 0, stream,
                     points_skip, x1);
  hipLaunchKernelGGL(interp_kernel, dim3(NS / 4, NB), dim3(256), 0, stream,
                     pptT, w3, idx3, x1);
  hipLaunchKernelGGL((gemm_bk64_kernel<0>), dim3(1024), dim3(256), 0, stream,
                     x1, W1b, y1b, pst1, (const float*)nullptr,
                     (const float*)nullptr, (const float*)nullptr);
  hipLaunchKernelGGL(statreduce_kernel, dim3(32), dim3(256), 0, stream, pst1, st1);
  hipLaunchKernelGGL((gemm_bk64_kernel<1>), dim3(1024), dim3(256), 0, stream,
                     y1b, W2b, y2b, pst2, st1, g1, b1);
  hipLaunchKernelGGL(statreduce_kernel, dim3(32), dim3(256), 0, stream, pst2, st2);
  if (full) {
    hipLaunchKernelGGL(bnrelu_tr_kernel, dim3(NS / 64, CO / 64, NB), dim3(256), 0,
                       stream, y2b, st2, g2, b2, out);
  } else {
    float* stage = (float*)d_ws;
    hipLaunchKernelGGL(bnrelu_tr_kernel, dim3(NS / 64, CO / 64, NB), dim3(256), 0,
                       stream, y2b, st2, g2, b2, stage);
    hipMemcpyAsync(out, stage, (size_t)NB * NS * CO * 4, hipMemcpyDeviceToDevice,
                   stream);
  }
}